// Round 11
// baseline (530.622 us; speedup 1.0000x reference)
//
#include <hip/hip_runtime.h>

#define LK   50      // look_back
#define NOUT 3
#define FF   64      // feature_num
#define BB   2048    // batch
#define BT   8       // batch rows per workgroup
#define NWG  (BB/BT) // 256 workgroups
#define NTHR 1024    // 16 waves

typedef unsigned short u16;
typedef unsigned int   u32;
typedef __attribute__((ext_vector_type(8))) short short8;
typedef __attribute__((ext_vector_type(4))) float f32x4;

#define MFMA16(a,b,c) __builtin_amdgcn_mfma_f32_16x16x32_bf16(a,b,c,0,0,0)
#define EPITCH 136   // s_enc row pitch in u16 (272B = 17*16: b128-aligned, 2-way banks)

__device__ __forceinline__ float sigf(float x) { return 1.0f / (1.0f + __expf(-x)); }
__device__ __forceinline__ float tanhff(float x) { return 1.0f - 2.0f / (__expf(2.0f * x) + 1.0f); }
__device__ __forceinline__ u16 f2b(float f) {
    union { float f; u32 u; } v; v.f = f;
    u32 r = v.u + 0x7fffu + ((v.u >> 16) & 1u);
    return (u16)(r >> 16);
}
__device__ __forceinline__ float b2f(u16 h) {
    union { u32 u; float f; } v; v.u = ((u32)h) << 16; return v.f;
}

__global__ __launch_bounds__(NTHR, 4)
void darnn_kernel(const float* __restrict__ x,
                  const float* __restrict__ eWih, const float* __restrict__ eWhh,
                  const float* __restrict__ ebih, const float* __restrict__ ebhh,
                  const float* __restrict__ aw,   const float* __restrict__ ab,
                  const float* __restrict__ dWih, const float* __restrict__ dWhh,
                  const float* __restrict__ dbih, const float* __restrict__ dbhh,
                  const float* __restrict__ ddw,  const float* __restrict__ ddb,
                  const float* __restrict__ dlw,  const float* __restrict__ dlb,
                  const float* __restrict__ fcw,  const float* __restrict__ fcb,
                  const float* __restrict__ ow,   const float* __restrict__ ob,
                  float* __restrict__ out)
{
    // encoder outputs (hi) LDS-resident: rt = r*50+t rows, 128 u16 each, pitch 136
    __shared__ __align__(16) u16 s_enc[400 * EPITCH];          // 108800 B
    __shared__ __align__(16) u32 s_pool[5824];                 //  23296 B (enc/dec overlay)
    __shared__ float s_c[8][128];                              //   4096 B
    __shared__ float s_g[512][9];                              //  18432 B
    __shared__ float s_ebias[512];                             //   2048 B
    __shared__ float s_dbias[512];                             //   2048 B
    // encoder overlay of s_pool
    u16  (*s_x)[16][80] = (u16 (*)[16][80])(s_pool);           // [2][16][80]
    u16  (*s_xin)[80]   = (u16 (*)[80])(s_pool + 1280);
    u16  (*s_h)[144]    = (u16 (*)[144])(s_pool + 1920);       // [hi k<128 | rows 8-15 = lo]
    float(*s_e)[64]     = (float (*)[64])(s_pool + 3072);
    // decoder overlay of s_pool
    u16  (*s_Adec)[272] = (u16 (*)[272])(s_pool);              // [ctx(0:128)|h(128:256)], lo rows 8-15
    float(*s_hp)[128]   = (float (*)[128])(s_pool + 2176);
    float(*s_spart)[400]= (float (*)[400])(s_pool + 3200);
    float(*s_alpha)[64] = (float (*)[64])(s_pool + 4800);
    float(*s_y1)[64]    = (float (*)[64])(s_pool + 5312);

    const int tid  = threadIdx.x;
    const int b0   = blockIdx.x * BT;
    const int wv   = tid >> 6;
    const int lane = tid & 63;
    const int quad = lane >> 4;
    const int l16  = lane & 15;
    const int n0   = wv * 32;           // this wave's 2 gate n-tiles

    // ---- preamble ----
    for (int i = tid; i < 5824; i += NTHR) s_pool[i] = 0;
    (&s_c[0][0])[tid] = 0.0f;
    if (tid < 512) { s_ebias[tid] = ebih[tid] + ebhh[tid]; s_dbias[tid] = dbih[tid] + dbhh[tid]; }
    if (tid < 512) {
        int r = tid >> 6, f = tid & 63;
        s_x[0][r][f] = f2b(x[((size_t)(b0 + r) * LK) * FF + f]);
    }
    // pin eW B-set from fp32: 2 tiles x 6 K-chunks = 48 VGPRs, whole t-loop
    short8 wf[12];
#pragma unroll
    for (int nn = 0; nn < 2; ++nn)
#pragma unroll
        for (int uc = 0; uc < 6; ++uc) {
            const int row = n0 + nn * 16 + l16;
            const int k0  = uc * 32 + quad * 8;
            const float* src = (uc < 2) ? (eWih + row * 64 + k0)
                                        : (eWhh + row * 128 + (k0 - 64));
            float4 wa = *(const float4*)src, wb = *(const float4*)(src + 4);
            short8 bv;
            bv[0]=(short)f2b(wa.x); bv[1]=(short)f2b(wa.y); bv[2]=(short)f2b(wa.z); bv[3]=(short)f2b(wa.w);
            bv[4]=(short)f2b(wb.x); bv[5]=(short)f2b(wb.y); bv[6]=(short)f2b(wb.z); bv[7]=(short)f2b(wb.w);
            wf[nn * 6 + uc] = bv;
        }
    __syncthreads();

    // ================= ENCODER: 50 steps, 4 barriers each =================
#pragma unroll 1
    for (int t = 0; t < LK; ++t) {
        const int pb = t & 1;

        // --- P1: attn (wv 0-3, B gathered fp32 inline) || x(t+1) prefetch (wv 12-15) ---
        if (wv < 4) {
            const int f0 = wv * 16 + l16;
            f32x4 acc = {0.f,0.f,0.f,0.f};
#pragma unroll 1
            for (int half = 0; half < 2; ++half) {
                float bw[3][8];
#pragma unroll
                for (int cc = 0; cc < 3; ++cc)
#pragma unroll
                    for (int j = 0; j < 8; ++j)
                        bw[cc][j] = aw[(size_t)t*12288 + ((half*3+cc)*32 + quad*8 + j)*64 + f0];
#pragma unroll
                for (int cc = 0; cc < 3; ++cc) {
                    const int c = half * 3 + cc;
                    short8 bv;
#pragma unroll
                    for (int j = 0; j < 8; ++j) bv[j] = (short)f2b(bw[cc][j]);
                    const u16* ap = (c < 2) ? &s_x[pb][l16][c*32 + quad*8]
                                            : &s_h[l16][(c-2)*32 + quad*8];
                    acc = MFMA16(*(const short8*)ap, bv, acc);
                }
            }
            float ev[4];
#pragma unroll
            for (int rg = 0; rg < 4; ++rg) ev[rg] = acc[rg] + __shfl_xor(acc[rg], 32, 64);
            const float abv = ab[t * FF + wv * 16 + l16];
            if (quad < 2) {
#pragma unroll
                for (int rg = 0; rg < 4; ++rg) s_e[quad*4 + rg][wv*16 + l16] = ev[rg] + abv;
            }
        } else if (wv >= 12) {
            if (t + 1 < LK) {
                const int ii = tid - 768;            // 0..255
                const int r = ii >> 5, p = ii & 31;  // 2 floats per thread
                const float2 xv = *(const float2*)(x + ((size_t)(b0 + r) * LK + (t + 1)) * FF + 2*p);
                *((u32*)&s_x[pb^1][r][0] + p) = (u32)f2b(xv.x) | ((u32)f2b(xv.y) << 16);
            }
        }
        __syncthreads();

        // --- P2: softmax, max-free (tanh(e) in [-1,1] -> exp safe) ---
        if (tid < 512) {
            const int r = tid >> 6;
            float ex = __expf(tanhff(s_e[r][lane]));
            float sm = ex;
#pragma unroll
            for (int m = 1; m < 64; m <<= 1) sm += __shfl_xor(sm, m, 64);
            s_xin[r][lane] = f2b(ex / sm * b2f(s_x[pb][r][lane]));
        }
        __syncthreads();

        // --- P3: gate GEMM, 16 waves, zero loads (B pinned), K=192 lo-folded ---
        {
            f32x4 a0 = {0.f,0.f,0.f,0.f}, a1 = {0.f,0.f,0.f,0.f};
#pragma unroll
            for (int c = 0; c < 6; ++c) {
                const u16* ap = (c < 2) ? &s_xin[l16][c*32 + quad*8]
                                        : &s_h[l16][(c-2)*32 + quad*8];
                short8 av = *(const short8*)ap;
                a0 = MFMA16(av, wf[c],   a0);
                a1 = MFMA16(av, wf[6+c], a1);
            }
            float v0[4], v1[4];
#pragma unroll
            for (int rg = 0; rg < 4; ++rg) {
                v0[rg] = a0[rg] + __shfl_xor(a0[rg], 32, 64);
                v1[rg] = a1[rg] + __shfl_xor(a1[rg], 32, 64);
            }
            if (quad < 2) {
#pragma unroll
                for (int rg = 0; rg < 4; ++rg) {
                    int r = quad*4 + rg;
                    s_g[n0 + l16][r]      = v0[rg];
                    s_g[n0 + 16 + l16][r] = v1[rg];
                }
            }
        }
        __syncthreads();

        // --- P4: gate combine + state update (hi/lo rows) + enc->LDS ---
        {
            const int u = tid & 127, r = tid >> 7;
            float gi = s_g[u][r]       + s_ebias[u];
            float gf = s_g[128 + u][r] + s_ebias[128 + u];
            float gg = s_g[256 + u][r] + s_ebias[256 + u];
            float go = s_g[384 + u][r] + s_ebias[384 + u];
            float c = sigf(gf) * s_c[r][u] + sigf(gi) * tanhff(gg);
            float h = sigf(go) * tanhff(c);
            s_c[r][u] = c;
            u16 hi = f2b(h);
            s_h[r][u]     = hi;
            s_h[r + 8][u] = f2b(h - b2f(hi));
            s_enc[(r * LK + t) * EPITCH + u] = hi;
        }
        __syncthreads();
    }

    // ================= DECODER: 3 steps, enc from LDS (hi only) =================
    for (int i = tid; i < 5824; i += NTHR) s_pool[i] = 0;
    (&s_c[0][0])[tid] = 0.0f;
    __syncthreads();

#pragma unroll 1
    for (int s = 0; s < NOUT; ++s) {
        // D1: hpart = h_de @ ddw[128:,:] + ddb (8 waves, K=128, lo folded; B inline fp32)
        if (wv < 8) {
            const int n = wv * 16 + l16;
            f32x4 acc = {0.f,0.f,0.f,0.f};
#pragma unroll
            for (int c = 0; c < 4; ++c) {
                const int k0 = 128 + c*32 + quad*8;
                short8 bv;
#pragma unroll
                for (int j = 0; j < 8; ++j) bv[j] = (short)f2b(ddw[(size_t)s*32768 + (k0+j)*128 + n]);
                short8 av = *(const short8*)&s_Adec[l16][128 + c*32 + quad*8];
                acc = MFMA16(av, bv, acc);
            }
            float vv[4];
#pragma unroll
            for (int rg = 0; rg < 4; ++rg) vv[rg] = acc[rg] + __shfl_xor(acc[rg], 32, 64);
            const float db = ddb[s * 128 + n];
            if (quad < 2) {
#pragma unroll
                for (int rg = 0; rg < 4; ++rg) s_hp[quad*4 + rg][n] = vv[rg] + db;
            }
        }
        __syncthreads();

        // D2: score GEMM [400,128-K] x [128,128], A from LDS (enc hi), B inline fp32
        {
            const int np = wv & 3, mq = wv >> 2, nb0 = np * 32;
            short8 bfr[8];
#pragma unroll
            for (int nn = 0; nn < 2; ++nn)
#pragma unroll
                for (int ks = 0; ks < 4; ++ks) {
                    const int n = nb0 + nn*16 + l16, k0 = ks*32 + quad*8;
                    short8 bv;
#pragma unroll
                    for (int j = 0; j < 8; ++j) bv[j] = (short)f2b(ddw[(size_t)s*32768 + (k0+j)*128 + n]);
                    bfr[nn*4 + ks] = bv;
                }
            const float dl0 = dlw[s*128 + nb0 + l16];
            const float dl1 = dlw[s*128 + nb0 + 16 + l16];
#pragma unroll 1
            for (int mt = mq; mt < 25; mt += 4) {
                const u16* ap = s_enc + (mt*16 + l16) * EPITCH + quad * 8;
                f32x4 a0 = {0.f,0.f,0.f,0.f}, a1 = {0.f,0.f,0.f,0.f};
#pragma unroll
                for (int c = 0; c < 4; ++c) {
                    short8 av = *(const short8*)(ap + c*32);
                    a0 = MFMA16(av, bfr[c],     a0);
                    a1 = MFMA16(av, bfr[4 + c], a1);
                }
#pragma unroll
                for (int rg = 0; rg < 4; ++rg) {
                    int rt = mt*16 + quad*4 + rg;
                    int r  = (rt * 1311) >> 16;          // rt/50 for rt<400
                    float v = tanhff(a0[rg] + s_hp[r][nb0 + l16]) * dl0
                            + tanhff(a1[rg] + s_hp[r][nb0 + 16 + l16]) * dl1;
                    v += __shfl_xor(v, 1, 64); v += __shfl_xor(v, 2, 64);
                    v += __shfl_xor(v, 4, 64); v += __shfl_xor(v, 8, 64);
                    if (l16 == 0) s_spart[np][rt] = v;
                }
            }
        }
        __syncthreads();

        // D3: softmax over t, max-free (|score| bounded ~5)
        if (tid < 512) {
            const int r = tid >> 6;
            float ex = 0.0f;
            if (lane < LK)
                ex = __expf(s_spart[0][r*LK + lane] + s_spart[1][r*LK + lane] +
                            s_spart[2][r*LK + lane] + s_spart[3][r*LK + lane] + dlb[s]);
            float sm = ex;
#pragma unroll
            for (int m = 1; m < 64; m <<= 1) sm += __shfl_xor(sm, m, 64);
            if (lane < LK) s_alpha[r][lane] = ex / sm;
        }
        __syncthreads();

        // D4: ctx = sum_t alpha * enc (LDS, fp32 acc); store hi/lo rows
        {
            const int jd = tid & 127, r = tid >> 7;
            const u16* ep = s_enc + r * LK * EPITCH + jd;
            float a = 0.0f;
#pragma unroll 10
            for (int tt = 0; tt < LK; ++tt) a += s_alpha[r][tt] * b2f(ep[tt * EPITCH]);
            u16 hi = f2b(a);
            s_Adec[r][jd]     = hi;
            s_Adec[r + 8][jd] = f2b(a - b2f(hi));
        }
        __syncthreads();

        // D5: decoder LSTM gates, K=384 lo-folded, B inline fp32 (contiguous rows)
        {
            const int nd0 = wv * 32;
            f32x4 a0 = {0.f,0.f,0.f,0.f}, a1 = {0.f,0.f,0.f,0.f};
#pragma unroll
            for (int c = 0; c < 12; ++c) {
                const int g = c >> 2, o = (c & 3) * 32 + quad * 8;
                const int boff = g * 128 + o;
                const float* p0, * p1;
                if (g < 2) { p0 = dWih + (nd0 + l16) * 256 + boff;       p1 = p0 + 16 * 256; }
                else       { p0 = dWhh + (nd0 + l16) * 128 + (boff - 256); p1 = p0 + 16 * 128; }
                float4 a4 = *(const float4*)p0, b4 = *(const float4*)(p0 + 4);
                float4 c4 = *(const float4*)p1, d4 = *(const float4*)(p1 + 4);
                short8 b0, b1;
                b0[0]=(short)f2b(a4.x); b0[1]=(short)f2b(a4.y); b0[2]=(short)f2b(a4.z); b0[3]=(short)f2b(a4.w);
                b0[4]=(short)f2b(b4.x); b0[5]=(short)f2b(b4.y); b0[6]=(short)f2b(b4.z); b0[7]=(short)f2b(b4.w);
                b1[0]=(short)f2b(c4.x); b1[1]=(short)f2b(c4.y); b1[2]=(short)f2b(c4.z); b1[3]=(short)f2b(c4.w);
                b1[4]=(short)f2b(d4.x); b1[5]=(short)f2b(d4.y); b1[6]=(short)f2b(d4.z); b1[7]=(short)f2b(d4.w);
                short8 av = *(const short8*)&s_Adec[l16][(g == 0 ? 0 : 128) + o];
                a0 = MFMA16(av, b0, a0);
                a1 = MFMA16(av, b1, a1);
            }
            float v0[4], v1[4];
#pragma unroll
            for (int rg = 0; rg < 4; ++rg) {
                v0[rg] = a0[rg] + __shfl_xor(a0[rg], 32, 64);
                v1[rg] = a1[rg] + __shfl_xor(a1[rg], 32, 64);
            }
            if (quad < 2) {
#pragma unroll
                for (int rg = 0; rg < 4; ++rg) {
                    int r = quad*4 + rg;
                    s_g[nd0 + l16][r]      = v0[rg];
                    s_g[nd0 + 16 + l16][r] = v1[rg];
                }
            }
        }
        __syncthreads();

        // D6: gate combine + state update (hi/lo rows)
        {
            const int u = tid & 127, r = tid >> 7;
            float gi = s_g[u][r]       + s_dbias[u];
            float gf = s_g[128 + u][r] + s_dbias[128 + u];
            float gg = s_g[256 + u][r] + s_dbias[256 + u];
            float go = s_g[384 + u][r] + s_dbias[384 + u];
            float c = sigf(gf) * s_c[r][u] + sigf(gi) * tanhff(gg);
            float h = sigf(go) * tanhff(c);
            s_c[r][u] = c;
            u16 hi = f2b(h);
            s_Adec[r][128 + u]     = hi;
            s_Adec[r + 8][128 + u] = f2b(h - b2f(hi));
        }
        __syncthreads();

        // D7: head y1 = tanh(h @ fc_w + fc_b) (4 waves, K=128 lo folded, B inline fp32)
        if (wv < 4) {
            const int n = wv * 16 + l16;
            f32x4 acc = {0.f,0.f,0.f,0.f};
#pragma unroll
            for (int c = 0; c < 4; ++c) {
                const int k0 = c*32 + quad*8;
                short8 bv;
#pragma unroll
                for (int j = 0; j < 8; ++j) bv[j] = (short)f2b(fcw[(size_t)s*8192 + (k0+j)*64 + n]);
                short8 av = *(const short8*)&s_Adec[l16][128 + c*32 + quad*8];
                acc = MFMA16(av, bv, acc);
            }
            float vv[4];
#pragma unroll
            for (int rg = 0; rg < 4; ++rg) vv[rg] = acc[rg] + __shfl_xor(acc[rg], 32, 64);
            const float fb = fcb[s * 64 + n];
            if (quad < 2) {
#pragma unroll
                for (int rg = 0; rg < 4; ++rg) s_y1[quad*4 + rg][n] = tanhff(vv[rg] + fb);
            }
        }
        __syncthreads();

        // D8: out = sigmoid(y1 @ out_w + out_b)
        if (tid < 512) {
            const int r = tid >> 6;
            float v = s_y1[r][lane] * ow[s * 64 + lane];
#pragma unroll
            for (int m = 1; m < 64; m <<= 1) v += __shfl_xor(v, m, 64);
            if (lane == 0) out[(b0 + r) * NOUT + s] = sigf(v + ob[s]);
        }
        __syncthreads();
    }
}

extern "C" void kernel_launch(void* const* d_in, const int* in_sizes, int n_in,
                              void* d_out, int out_size, void* d_ws, size_t ws_size,
                              hipStream_t stream) {
    const float* x    = (const float*)d_in[0];
    const float* eWih = (const float*)d_in[1];
    const float* eWhh = (const float*)d_in[2];
    const float* ebih = (const float*)d_in[3];
    const float* ebhh = (const float*)d_in[4];
    const float* aw   = (const float*)d_in[5];
    const float* ab   = (const float*)d_in[6];
    const float* dWih = (const float*)d_in[7];
    const float* dWhh = (const float*)d_in[8];
    const float* dbih = (const float*)d_in[9];
    const float* dbhh = (const float*)d_in[10];
    const float* ddw  = (const float*)d_in[11];
    const float* ddb  = (const float*)d_in[12];
    const float* dlw  = (const float*)d_in[13];
    const float* dlb  = (const float*)d_in[14];
    const float* fcw  = (const float*)d_in[15];
    const float* fcb  = (const float*)d_in[16];
    const float* ow   = (const float*)d_in[17];
    const float* ob   = (const float*)d_in[18];
    float* out = (float*)d_out;

    darnn_kernel<<<NWG, NTHR, 0, stream>>>(x, eWih, eWhh, ebih, ebhh, aw, ab,
                                           dWih, dWhh, dbih, dbhh, ddw, ddb,
                                           dlw, dlb, fcw, fcb, ow, ob, out);
}

// Round 12
// 348.709 us; speedup vs baseline: 1.5217x; 1.5217x over previous
//
#include <hip/hip_runtime.h>

#define LK   50      // look_back
#define NOUT 3
#define FF   64      // feature_num
#define BB   2048    // batch
#define BT   8       // batch rows per workgroup
#define NWG  (BB/BT) // 256 workgroups
#define NTHR 1024    // 16 waves

typedef unsigned short u16;
typedef unsigned int   u32;
typedef __attribute__((ext_vector_type(8))) short short8;
typedef __attribute__((ext_vector_type(4))) float f32x4;

#define MFMA16(a,b,c) __builtin_amdgcn_mfma_f32_16x16x32_bf16(a,b,c,0,0,0)
#define EPITCH 136   // s_enc row pitch in u16

// pre-converted bf16 weight buffers (device globals; rewritten every launch)
__device__ u16 g_awT [(size_t)LK*64*192];  // attn_w^T, [t][c][k]  k:[xt(64)|h(128)]
__device__ u16 g_eW  [512*192];            // enc LSTM, [gate][k]
__device__ u16 g_dW  [512*384];            // dec LSTM, [gate][k]  k:[ctx|h|h]
__device__ u16 g_ddwT[NOUT*128*256];       // dd_w^T,   [s][n][k]
__device__ u16 g_fcwT[NOUT*64*128];        // fc_w^T,   [s][n][k]

__device__ __forceinline__ float sigf(float x) { return 1.0f / (1.0f + __expf(-x)); }
__device__ __forceinline__ float tanhff(float x) { return 1.0f - 2.0f / (__expf(2.0f * x) + 1.0f); }
__device__ __forceinline__ u16 f2b(float f) {
    union { float f; u32 u; } v; v.f = f;
    u32 r = v.u + 0x7fffu + ((v.u >> 16) & 1u);
    return (u16)(r >> 16);
}
__device__ __forceinline__ float b2f(u16 h) {
    union { u32 u; float f; } v; v.u = ((u32)h) << 16; return v.f;
}

// single merged convert dispatch: blocks 0..49 transpose awT (LDS tile),
// blocks 50.. grid-stride the other weights (verified layouts from R10)
__global__ __launch_bounds__(256)
void convert_kernel(const float* __restrict__ aw,
                    const float* __restrict__ eWih, const float* __restrict__ eWhh,
                    const float* __restrict__ dWih, const float* __restrict__ dWhh,
                    const float* __restrict__ ddw,  const float* __restrict__ fcw)
{
    __shared__ u16 tile[192*66];
    if (blockIdx.x < LK) {
        const int t = blockIdx.x, tid = threadIdx.x;
        for (int i = tid; i < 192*64; i += 256) {
            int k = i >> 6, c = i & 63;
            tile[k*66 + c] = f2b(aw[(size_t)t*12288 + i]);
        }
        __syncthreads();
        u32* dst = (u32*)g_awT + (size_t)t * 6144;
        for (int j = tid; j < 6144; j += 256) {
            int c = j / 96, w = j % 96;
            dst[j] = (u32)tile[(2*w)*66 + c] | ((u32)tile[(2*w+1)*66 + c] << 16);
        }
        return;
    }
    const int gid = (blockIdx.x - LK) * blockDim.x + threadIdx.x;
    const int stride = (gridDim.x - LK) * blockDim.x;
    for (int i = gid; i < 512*192; i += stride) {
        int j = i / 192, k = i % 192;
        g_eW[i] = f2b(k < 64 ? eWih[j*64 + k] : eWhh[j*128 + (k-64)]);
    }
    for (int i = gid; i < 512*384; i += stride) {
        int j = i / 384, k = i % 384;
        g_dW[i] = f2b(k < 256 ? dWih[j*256 + k] : dWhh[j*128 + (k-256)]);
    }
    for (int i = gid; i < NOUT*256*128; i += stride) {
        int s = i / 32768, rm = i % 32768, k = rm / 128, n = rm % 128;
        g_ddwT[(size_t)s*32768 + n*256 + k] = f2b(ddw[i]);
    }
    for (int i = gid; i < NOUT*128*64; i += stride) {
        int s = i / 8192, rm = i % 8192, k = rm / 64, n = rm % 64;
        g_fcwT[(size_t)s*8192 + n*128 + k] = f2b(fcw[i]);
    }
}

__global__ __launch_bounds__(NTHR, 4)
void darnn_kernel(const float* __restrict__ x,
                  const float* __restrict__ ab,
                  const float* __restrict__ ebih, const float* __restrict__ ebhh,
                  const float* __restrict__ dbih, const float* __restrict__ dbhh,
                  const float* __restrict__ ddb,
                  const float* __restrict__ dlw,  const float* __restrict__ dlb,
                  const float* __restrict__ fcb,
                  const float* __restrict__ ow,   const float* __restrict__ ob,
                  float* __restrict__ out)
{
    // encoder outputs (hi) LDS-resident: rt = r*50+t rows, pitch 136 u16
    __shared__ __align__(16) u16 s_enc[400 * EPITCH];          // 108800 B
    __shared__ __align__(16) u32 s_pool[5824];                 //  23296 B (enc/dec overlay)
    __shared__ float s_c[8][128];
    __shared__ float s_g[512][9];
    __shared__ float s_ebias[512];
    __shared__ float s_dbias[512];
    // encoder overlay
    u16  (*s_x)[16][80] = (u16 (*)[16][80])(s_pool);           // [2][16][80]
    u16  (*s_xin)[80]   = (u16 (*)[80])(s_pool + 1280);
    u16  (*s_h)[144]    = (u16 (*)[144])(s_pool + 1920);       // hi rows 0-7, lo rows 8-15
    float(*s_e)[64]     = (float (*)[64])(s_pool + 3072);
    // decoder overlay
    u16  (*s_Adec)[272] = (u16 (*)[272])(s_pool);              // [ctx|h], lo rows 8-15
    float(*s_hp)[128]   = (float (*)[128])(s_pool + 2176);
    float(*s_spart)[400]= (float (*)[400])(s_pool + 3200);
    float(*s_alpha)[64] = (float (*)[64])(s_pool + 4800);
    float(*s_y1)[64]    = (float (*)[64])(s_pool + 5312);

    const int tid  = threadIdx.x;
    const int b0   = blockIdx.x * BT;
    const int wv   = tid >> 6;
    const int lane = tid & 63;
    const int quad = lane >> 4;
    const int l16  = lane & 15;
    const int n0   = wv * 32;

    // ---- preamble ----
    for (int i = tid; i < 5824; i += NTHR) s_pool[i] = 0;
    (&s_c[0][0])[tid] = 0.0f;
    if (tid < 512) { s_ebias[tid] = ebih[tid] + ebhh[tid]; s_dbias[tid] = dbih[tid] + dbhh[tid]; }
    if (tid < 512) {
        int r = tid >> 6, f = tid & 63;
        s_x[0][r][f] = f2b(x[((size_t)(b0 + r) * LK) * FF + f]);
    }
    // pin eW B-set (bf16 global): 2 tiles x 6 K-chunks = 48 VGPRs, whole t-loop
    short8 wf[12];
#pragma unroll
    for (int nn = 0; nn < 2; ++nn)
#pragma unroll
        for (int uc = 0; uc < 6; ++uc)
            wf[nn*6+uc] = *(const short8*)(g_eW + (size_t)(n0 + nn*16 + l16) * 192 + uc*32 + quad*8);
    __syncthreads();

    // ================= ENCODER: 50 steps, 4 barriers each =================
#pragma unroll 1
    for (int t = 0; t < LK; ++t) {
        const int pb = t & 1;

        // --- P1: attn (wv 0-3, B bf16 16B loads) || x(t+1) prefetch (wv 12-15) ---
        if (wv < 4) {
            const int f0 = wv * 16 + l16;
            const u16* bp = g_awT + (size_t)t * 12288 + f0 * 192 + quad * 8;
            short8 bfr[6];
#pragma unroll
            for (int uc = 0; uc < 6; ++uc) bfr[uc] = *(const short8*)(bp + uc*32);
            f32x4 acc = {0.f,0.f,0.f,0.f};
#pragma unroll
            for (int c = 0; c < 6; ++c) {
                const u16* ap = (c < 2) ? &s_x[pb][l16][c*32 + quad*8]
                                        : &s_h[l16][(c-2)*32 + quad*8];
                acc = MFMA16(*(const short8*)ap, bfr[c], acc);
            }
            float ev[4];
#pragma unroll
            for (int rg = 0; rg < 4; ++rg) ev[rg] = acc[rg] + __shfl_xor(acc[rg], 32, 64);
            const float abv = ab[t * FF + f0];
            if (quad < 2) {
#pragma unroll
                for (int rg = 0; rg < 4; ++rg) s_e[quad*4 + rg][f0] = ev[rg] + abv;
            }
        } else if (wv >= 12) {
            if (t + 1 < LK) {
                const int ii = tid - 768;
                const int r = ii >> 5, p = ii & 31;
                const float2 xv = *(const float2*)(x + ((size_t)(b0 + r) * LK + (t + 1)) * FF + 2*p);
                *((u32*)&s_x[pb^1][r][0] + p) = (u32)f2b(xv.x) | ((u32)f2b(xv.y) << 16);
            }
        }
        __syncthreads();

        // --- P2: softmax, max-free (tanh(e) in [-1,1]) ---
        if (tid < 512) {
            const int r = tid >> 6;
            float ex = __expf(tanhff(s_e[r][lane]));
            float sm = ex;
#pragma unroll
            for (int m = 1; m < 64; m <<= 1) sm += __shfl_xor(sm, m, 64);
            s_xin[r][lane] = f2b(ex / sm * b2f(s_x[pb][r][lane]));
        }
        __syncthreads();

        // --- P3: gate GEMM, 16 waves, zero loads (B pinned), K=192 lo-folded ---
        {
            f32x4 a0 = {0.f,0.f,0.f,0.f}, a1 = {0.f,0.f,0.f,0.f};
#pragma unroll
            for (int c = 0; c < 6; ++c) {
                const u16* ap = (c < 2) ? &s_xin[l16][c*32 + quad*8]
                                        : &s_h[l16][(c-2)*32 + quad*8];
                short8 av = *(const short8*)ap;
                a0 = MFMA16(av, wf[c],   a0);
                a1 = MFMA16(av, wf[6+c], a1);
            }
            float v0[4], v1[4];
#pragma unroll
            for (int rg = 0; rg < 4; ++rg) {
                v0[rg] = a0[rg] + __shfl_xor(a0[rg], 32, 64);
                v1[rg] = a1[rg] + __shfl_xor(a1[rg], 32, 64);
            }
            if (quad < 2) {
#pragma unroll
                for (int rg = 0; rg < 4; ++rg) {
                    int r = quad*4 + rg;
                    s_g[n0 + l16][r]      = v0[rg];
                    s_g[n0 + 16 + l16][r] = v1[rg];
                }
            }
        }
        __syncthreads();

        // --- P4: gate combine + state update (hi/lo rows) + enc->LDS ---
        {
            const int u = tid & 127, r = tid >> 7;
            float gi = s_g[u][r]       + s_ebias[u];
            float gf = s_g[128 + u][r] + s_ebias[128 + u];
            float gg = s_g[256 + u][r] + s_ebias[256 + u];
            float go = s_g[384 + u][r] + s_ebias[384 + u];
            float c = sigf(gf) * s_c[r][u] + sigf(gi) * tanhff(gg);
            float h = sigf(go) * tanhff(c);
            s_c[r][u] = c;
            u16 hi = f2b(h);
            s_h[r][u]     = hi;
            s_h[r + 8][u] = f2b(h - b2f(hi));
            s_enc[(r * LK + t) * EPITCH + u] = hi;
        }
        __syncthreads();
    }

    // ================= DECODER: 3 steps, enc from LDS (hi only) =================
    for (int i = tid; i < 5824; i += NTHR) s_pool[i] = 0;
    (&s_c[0][0])[tid] = 0.0f;
    __syncthreads();

#pragma unroll 1
    for (int s = 0; s < NOUT; ++s) {
        // D1: hpart = h_de @ ddw[128:,:] + ddb (8 waves, K=128 lo-folded, B bf16)
        if (wv < 8) {
            const int n = wv * 16 + l16;
            f32x4 acc = {0.f,0.f,0.f,0.f};
            const u16* bp = g_ddwT + s * 32768 + n * 256 + 128 + quad * 8;
#pragma unroll
            for (int c = 0; c < 4; ++c) {
                short8 av = *(const short8*)&s_Adec[l16][128 + c*32 + quad*8];
                acc = MFMA16(av, *(const short8*)(bp + c*32), acc);
            }
            float vv[4];
#pragma unroll
            for (int rg = 0; rg < 4; ++rg) vv[rg] = acc[rg] + __shfl_xor(acc[rg], 32, 64);
            const float db = ddb[s * 128 + n];
            if (quad < 2) {
#pragma unroll
                for (int rg = 0; rg < 4; ++rg) s_hp[quad*4 + rg][n] = vv[rg] + db;
            }
        }
        __syncthreads();

        // D2: score GEMM [400,128-K] x [128,128], A from LDS enc(hi), B bf16
        {
            const int np = wv & 3, mq = wv >> 2, nb0 = np * 32;
            short8 bfr[8];
            const u16* bp = g_ddwT + s * 32768 + (nb0 + l16) * 256 + quad * 8;
#pragma unroll
            for (int nn = 0; nn < 2; ++nn)
#pragma unroll
                for (int ks = 0; ks < 4; ++ks)
                    bfr[nn*4+ks] = *(const short8*)(bp + nn*4096 + ks*32);
            const float dl0 = dlw[s*128 + nb0 + l16];
            const float dl1 = dlw[s*128 + nb0 + 16 + l16];
#pragma unroll 1
            for (int mt = mq; mt < 25; mt += 4) {
                const u16* ap = s_enc + (mt*16 + l16) * EPITCH + quad * 8;
                f32x4 a0 = {0.f,0.f,0.f,0.f}, a1 = {0.f,0.f,0.f,0.f};
#pragma unroll
                for (int c = 0; c < 4; ++c) {
                    short8 av = *(const short8*)(ap + c*32);
                    a0 = MFMA16(av, bfr[c],     a0);
                    a1 = MFMA16(av, bfr[4 + c], a1);
                }
#pragma unroll
                for (int rg = 0; rg < 4; ++rg) {
                    int rt = mt*16 + quad*4 + rg;
                    int r  = (rt * 1311) >> 16;          // rt/50 for rt<400
                    float v = tanhff(a0[rg] + s_hp[r][nb0 + l16]) * dl0
                            + tanhff(a1[rg] + s_hp[r][nb0 + 16 + l16]) * dl1;
                    v += __shfl_xor(v, 1, 64); v += __shfl_xor(v, 2, 64);
                    v += __shfl_xor(v, 4, 64); v += __shfl_xor(v, 8, 64);
                    if (l16 == 0) s_spart[np][rt] = v;
                }
            }
        }
        __syncthreads();

        // D3: softmax over t, max-free (scores bounded)
        if (tid < 512) {
            const int r = tid >> 6;
            float ex = 0.0f;
            if (lane < LK)
                ex = __expf(s_spart[0][r*LK + lane] + s_spart[1][r*LK + lane] +
                            s_spart[2][r*LK + lane] + s_spart[3][r*LK + lane] + dlb[s]);
            float sm = ex;
#pragma unroll
            for (int m = 1; m < 64; m <<= 1) sm += __shfl_xor(sm, m, 64);
            if (lane < LK) s_alpha[r][lane] = ex / sm;
        }
        __syncthreads();

        // D4: ctx = sum_t alpha * enc (LDS, fp32); store hi/lo rows
        {
            const int jd = tid & 127, r = tid >> 7;
            const u16* ep = s_enc + r * LK * EPITCH + jd;
            float a = 0.0f;
#pragma unroll 10
            for (int tt = 0; tt < LK; ++tt) a += s_alpha[r][tt] * b2f(ep[tt * EPITCH]);
            u16 hi = f2b(a);
            s_Adec[r][jd]     = hi;
            s_Adec[r + 8][jd] = f2b(a - b2f(hi));
        }
        __syncthreads();

        // D5: decoder LSTM gates, K=384 lo-folded, B bf16 (g_dW)
        {
            const int nd0 = wv * 32;
            f32x4 a0 = {0.f,0.f,0.f,0.f}, a1 = {0.f,0.f,0.f,0.f};
            const u16* bp0 = g_dW + (nd0 + l16) * 384 + quad * 8;
            const u16* bp1 = bp0 + 16 * 384;
#pragma unroll
            for (int c = 0; c < 12; ++c) {
                const int g = c >> 2, o = (c & 3) * 32;
                const int aoff = (g == 0 ? 0 : 128) + o;
                const int boff = g * 128 + o;
                short8 av = *(const short8*)&s_Adec[l16][aoff + quad*8];
                a0 = MFMA16(av, *(const short8*)(bp0 + boff), a0);
                a1 = MFMA16(av, *(const short8*)(bp1 + boff), a1);
            }
            float v0[4], v1[4];
#pragma unroll
            for (int rg = 0; rg < 4; ++rg) {
                v0[rg] = a0[rg] + __shfl_xor(a0[rg], 32, 64);
                v1[rg] = a1[rg] + __shfl_xor(a1[rg], 32, 64);
            }
            if (quad < 2) {
#pragma unroll
                for (int rg = 0; rg < 4; ++rg) {
                    int r = quad*4 + rg;
                    s_g[nd0 + l16][r]      = v0[rg];
                    s_g[nd0 + 16 + l16][r] = v1[rg];
                }
            }
        }
        __syncthreads();

        // D6: gate combine + state update (hi/lo rows)
        {
            const int u = tid & 127, r = tid >> 7;
            float gi = s_g[u][r]       + s_dbias[u];
            float gf = s_g[128 + u][r] + s_dbias[128 + u];
            float gg = s_g[256 + u][r] + s_dbias[256 + u];
            float go = s_g[384 + u][r] + s_dbias[384 + u];
            float c = sigf(gf) * s_c[r][u] + sigf(gi) * tanhff(gg);
            float h = sigf(go) * tanhff(c);
            s_c[r][u] = c;
            u16 hi = f2b(h);
            s_Adec[r][128 + u]     = hi;
            s_Adec[r + 8][128 + u] = f2b(h - b2f(hi));
        }
        __syncthreads();

        // D7: head y1 = tanh(h @ fc_w + fc_b) (4 waves, K=128 lo-folded, B bf16)
        if (wv < 4) {
            const int n = wv * 16 + l16;
            f32x4 acc = {0.f,0.f,0.f,0.f};
            const u16* bp = g_fcwT + s * 8192 + n * 128 + quad * 8;
#pragma unroll
            for (int c = 0; c < 4; ++c) {
                short8 av = *(const short8*)&s_Adec[l16][128 + c*32 + quad*8];
                acc = MFMA16(av, *(const short8*)(bp + c*32), acc);
            }
            float vv[4];
#pragma unroll
            for (int rg = 0; rg < 4; ++rg) vv[rg] = acc[rg] + __shfl_xor(acc[rg], 32, 64);
            const float fb = fcb[s * 64 + n];
            if (quad < 2) {
#pragma unroll
                for (int rg = 0; rg < 4; ++rg) s_y1[quad*4 + rg][n] = tanhff(vv[rg] + fb);
            }
        }
        __syncthreads();

        // D8: out = sigmoid(y1 @ out_w + out_b)
        if (tid < 512) {
            const int r = tid >> 6;
            float v = s_y1[r][lane] * ow[s * 64 + lane];
#pragma unroll
            for (int m = 1; m < 64; m <<= 1) v += __shfl_xor(v, m, 64);
            if (lane == 0) out[(b0 + r) * NOUT + s] = sigf(v + ob[s]);
        }
        __syncthreads();
    }
}

extern "C" void kernel_launch(void* const* d_in, const int* in_sizes, int n_in,
                              void* d_out, int out_size, void* d_ws, size_t ws_size,
                              hipStream_t stream) {
    const float* x    = (const float*)d_in[0];
    const float* eWih = (const float*)d_in[1];
    const float* eWhh = (const float*)d_in[2];
    const float* ebih = (const float*)d_in[3];
    const float* ebhh = (const float*)d_in[4];
    const float* aw   = (const float*)d_in[5];
    const float* ab   = (const float*)d_in[6];
    const float* dWih = (const float*)d_in[7];
    const float* dWhh = (const float*)d_in[8];
    const float* dbih = (const float*)d_in[9];
    const float* dbhh = (const float*)d_in[10];
    const float* ddw  = (const float*)d_in[11];
    const float* ddb  = (const float*)d_in[12];
    const float* dlw  = (const float*)d_in[13];
    const float* dlb  = (const float*)d_in[14];
    const float* fcw  = (const float*)d_in[15];
    const float* fcb  = (const float*)d_in[16];
    const float* ow   = (const float*)d_in[17];
    const float* ob   = (const float*)d_in[18];
    float* out = (float*)d_out;

    convert_kernel<<<LK + 512, 256, 0, stream>>>(aw, eWih, eWhh, dWih, dWhh, ddw, fcw);
    darnn_kernel<<<NWG, NTHR, 0, stream>>>(x, ab, ebih, ebhh, dbih, dbhh, ddb,
                                           dlw, dlb, fcb, ow, ob, out);
}